// Round 6
// baseline (189.047 us; speedup 1.0000x reference)
//
#include <hip/hip_runtime.h>
#include <hip/hip_bf16.h>

typedef _Float16 f16;
typedef __attribute__((ext_vector_type(2))) _Float16 f16x2;
typedef __attribute__((ext_vector_type(8))) _Float16 f16x8;
typedef __attribute__((ext_vector_type(16))) float f32x16;

#define BNSCL 0.9999950000375f   /* 1/sqrt(1+1e-5) */

// ws layout (bytes):
//   scores f16 : [0, 4 MB)
//   G      f16 : [4 MB, 12 MB)      8192 groups x 512 (om = o*8+m)
//   wpf    f16 : [12 MB, +128 KB)   W+ = wbD+wbR in A-frag order
//   wdb    f16 : [12.25 MB, +64 KB) -wbD in B-frag order (for k_gprep)

// ---------------------------------------------------------------------------
// Kernel 1: per-point scores MLP + softmax (weights in LDS, 2 pts/thread),
// f16 output. Fused prep:
//   blocks [0,256):   wpf[((ot*32+ks)*64+lane)*8+j] = f16(wbD+wbR) A-frag order
//   blocks [256,384): wdb[((T*4+s)*64+lane)*8+j]    = f16(-wbD)    B-frag order
// ---------------------------------------------------------------------------
__global__ __launch_bounds__(256) void k_scores(
    const float* __restrict__ xyz,
    const float* __restrict__ w1, const float* __restrict__ g1, const float* __restrict__ be1,
    const float* __restrict__ w2, const float* __restrict__ g2, const float* __restrict__ be2,
    const float* __restrict__ w3, const float* __restrict__ g3, const float* __restrict__ be3,
    const float* __restrict__ w4, const float* __restrict__ b4,
    const float* __restrict__ wb, f16* __restrict__ wpf, f16* __restrict__ wdb,
    f16* __restrict__ scores)
{
    __shared__ float lw[856];
    const int tid = threadIdx.x;
    const int bx  = blockIdx.x;

    if (bx < 256) {
        int idx  = bx * 256 + tid;             // 0..65535
        int j    = idx & 7;
        int lane = (idx >> 3) & 63;
        int ks   = (idx >> 9) & 31;
        int ot   = idx >> 14;                  // 0..1
        int c    = ks * 2 + (lane >> 5);       // 0..63
        int o    = ot * 32 + (lane & 31);
        float v  = wb[(c * 8 + j) * 64 + o] + wb[((c + 64) * 8 + j) * 64 + o];
        wpf[idx] = (f16)v;
    } else if (bx < 384) {
        int idx  = (bx - 256) * 256 + tid;     // 0..32767
        int j    = idx & 7;
        int lane = (idx >> 3) & 63;
        int s    = (idx >> 9) & 3;
        int T    = idx >> 11;                  // 0..15
        int om   = T * 32 + (lane & 31);
        int o    = om >> 3, m = om & 7;
        int c    = s * 16 + (lane >> 5) * 8 + j;
        wdb[idx] = (f16)(-wb[(c * 8 + m) * 64 + o]);
    }

    if (tid < 112) lw[tid] = w1[tid];
    lw[112 + tid] = w2[tid];
    lw[368 + tid] = w3[tid];
    if (tid < 128) lw[624 + tid] = w4[tid];
    if (tid < 8)   lw[752 + tid] = b4[tid];
    if (tid < 16) {
        lw[760 + tid] = g1[tid] * BNSCL;  lw[776 + tid] = be1[tid];
        lw[792 + tid] = g2[tid] * BNSCL;  lw[808 + tid] = be2[tid];
        lw[824 + tid] = g3[tid] * BNSCL;  lw[840 + tid] = be3[tid];
    }
    __syncthreads();

    float in7[2][7], h1[2][16], h2[2][16], s[2][8];

#pragma unroll
    for (int q = 0; q < 2; ++q) {
        int g = bx * 512 + q * 256 + tid;
        int b = g >> 15;
        int p = g & 32767;
        int pc = p & ~31;
        const float* xb = xyz + (size_t)b * 98304;
        float cx = xb[pc], cy = xb[32768 + pc], cz = xb[65536 + pc];
        float dx = xb[p] - cx, dy = xb[32768 + p] - cy, dz = xb[65536 + p] - cz;
        in7[q][0] = cx; in7[q][1] = cy; in7[q][2] = cz;
        in7[q][3] = dx; in7[q][4] = dy; in7[q][5] = dz;
        in7[q][6] = sqrtf(dx * dx + dy * dy + dz * dz);
    }

#pragma unroll
    for (int o = 0; o < 16; ++o) {
        float a0 = 0.f, a1 = 0.f;
#pragma unroll
        for (int c = 0; c < 7; ++c) {
            float w = lw[o * 7 + c];
            a0 += w * in7[0][c]; a1 += w * in7[1][c];
        }
        float gs = lw[760 + o], bb = lw[776 + o];
        h1[0][o] = fmaxf(a0 * gs + bb, 0.f);
        h1[1][o] = fmaxf(a1 * gs + bb, 0.f);
    }
#pragma unroll
    for (int o = 0; o < 16; ++o) {
        float a0 = 0.f, a1 = 0.f;
#pragma unroll
        for (int c = 0; c < 16; ++c) {
            float w = lw[112 + o * 16 + c];
            a0 += w * h1[0][c]; a1 += w * h1[1][c];
        }
        float gs = lw[792 + o], bb = lw[808 + o];
        h2[0][o] = fmaxf(a0 * gs + bb, 0.f);
        h2[1][o] = fmaxf(a1 * gs + bb, 0.f);
    }
#pragma unroll
    for (int o = 0; o < 16; ++o) {
        float a0 = 0.f, a1 = 0.f;
#pragma unroll
        for (int c = 0; c < 16; ++c) {
            float w = lw[368 + o * 16 + c];
            a0 += w * h2[0][c]; a1 += w * h2[1][c];
        }
        float gs = lw[824 + o], bb = lw[840 + o];
        h1[0][o] = fmaxf(a0 * gs + bb, 0.f);
        h1[1][o] = fmaxf(a1 * gs + bb, 0.f);
    }
#pragma unroll
    for (int o = 0; o < 8; ++o) {
        float bb = lw[752 + o];
        float a0 = bb, a1 = bb;
#pragma unroll
        for (int c = 0; c < 16; ++c) {
            float w = lw[624 + o * 16 + c];
            a0 += w * h1[0][c]; a1 += w * h1[1][c];
        }
        s[0][o] = a0; s[1][o] = a1;
    }

#pragma unroll
    for (int q = 0; q < 2; ++q) {
        int g = bx * 512 + q * 256 + tid;
        float mx = s[q][0];
#pragma unroll
        for (int i = 1; i < 8; ++i) mx = fmaxf(mx, s[q][i]);
        float sum = 0.f;
#pragma unroll
        for (int i = 0; i < 8; ++i) { s[q][i] = __expf(s[q][i] - mx); sum += s[q][i]; }
        float inv = 1.f / sum;
        f16x8 o8;
#pragma unroll
        for (int i = 0; i < 8; ++i) o8[i] = (f16)(s[q][i] * inv);
        *(f16x8*)(scores + (size_t)g * 8) = o8;
    }
}

// ---------------------------------------------------------------------------
// Kernel 1b: G[g][om] = -sum_{c<64} fcenter[c,g] * wbD[c,m,o]  (f16)
// One block = 32 groups. Center gather = one 128B line per (c,g) -> reads all
// of feat's lines once (doubles as L3 prefetch for k_main).
// MFMA 32x32x16: A = fc (g x c) from LDS, B = -wbD (c x om) from wdb (global).
// ---------------------------------------------------------------------------
__global__ __launch_bounds__(256) void k_gprep(
    const float* __restrict__ feat,
    const f16* __restrict__ wdb,
    f16* __restrict__ G)
{
    __shared__ f16 fc16[32 * 64];   // [g][c], 16B chunks XOR-swizzled by g

    const int tid = threadIdx.x;
    const int blk = blockIdx.x;            // 0..255
    const int b   = blk >> 5;              // 32 blocks / batch
    const int nb  = (blk & 31) * 32;       // first group within batch
    const float* fb = feat + (size_t)b * 2097152 + (size_t)nb * 32;

#pragma unroll
    for (int it = 0; it < 8; ++it) {
        int idx = it * 256 + tid;          // 0..2047 = (c,g)
        int c = idx >> 5, g = idx & 31;
        float v = fb[(size_t)c * 32768 + g * 32];
        int cb = c >> 3, j = c & 7;
        fc16[g * 64 + ((cb ^ (g & 7)) * 8) + j] = (f16)v;
    }
    __syncthreads();

    const int lane = tid & 63, wave = tid >> 6;
    const int l31  = lane & 31, lh = lane >> 5;
    const int gbase = blk * 32;

#pragma unroll
    for (int tt = 0; tt < 4; ++tt) {
        int T = wave * 4 + tt;             // om-tile 0..15
        f32x16 acc = {};
#pragma unroll
        for (int s = 0; s < 4; ++s) {
            int cb = s * 2 + lh;
            f16x8 af = *(const f16x8*)&fc16[l31 * 64 + ((cb ^ (l31 & 7)) * 8)];
            f16x8 bf = *(const f16x8*)&wdb[(((T * 4 + s) * 64) + lane) * 8];
            acc = __builtin_amdgcn_mfma_f32_32x32x16_f16(af, bf, acc, 0, 0, 0);
        }
#pragma unroll
        for (int r = 0; r < 16; ++r) {
            int grow = (r & 3) + 8 * (r >> 2) + 4 * lh;
            G[(size_t)(gbase + grow) * 512 + T * 32 + l31] = (f16)acc[r];
        }
    }
}

// ---------------------------------------------------------------------------
// Kernel 2: main einsum. out = GEMM(W+, f*s)  [K=512]  + G-correction MFMA.
// Block = 512 thr (8 waves) x 64 pts/wave = 512 points, ALL 64 outputs.
// LDS = W+ frag-ordered 64 KB, staged once. Per iter: 2 ds_read_b128 +
// 2 feat dword + 8 pk_mul + 4 MFMA. Epilogue: 4 correction MFMAs (A = G-frag
// zero-masked on lh=1, B = score vector), BN, ReLU, coalesced store.
// ---------------------------------------------------------------------------
__global__ __launch_bounds__(512, 4) void k_main(
    const float* __restrict__ feat,
    const f16* __restrict__ scores,
    const f16* __restrict__ wpf,
    const f16* __restrict__ G,
    const float* __restrict__ bn_g, const float* __restrict__ bn_b,
    float* __restrict__ out)
{
    __shared__ __align__(16) f16 lwb[32768];    // 64 KB, same flat order as wpf

    const int tid  = threadIdx.x;
    const int lane = tid & 63;
    const int wave = tid >> 6;          // 0..7
    const int l31  = lane & 31;
    const int lh   = lane >> 5;         // 0..1

    const int pblock = blockIdx.x * 512;
    const int b    = pblock >> 15;
    const int pt0  = (pblock & 32767) + wave * 64;   // 32-aligned
    const int pc0  = pt0 + l31;
    const int pc1  = pc0 + 32;
    const int grp0 = (pblock + wave * 64) >> 5;      // global group ids
    const int grp1 = grp0 + 1;

    // stage W+ fragments (identical flat layout -> plain vector copy)
#pragma unroll
    for (int it = 0; it < 16; ++it) {
        int idx = it * 512 + tid;                    // 16B chunks, 0..8191
        *(int4*)&lwb[idx << 3] = *(const int4*)&wpf[idx << 3];
    }
    __syncthreads();

    const float* fb = feat + (size_t)b * 2097152;

    const int gpt = pblock + wave * 64 + l31;
    f16x8 sv0 = *(const f16x8*)(scores + (size_t)gpt * 8);
    f16x8 sv1 = *(const f16x8*)(scores + (size_t)(gpt + 32) * 8);
    const f16x2 s0a = {sv0[0], sv0[1]}, s0b = {sv0[2], sv0[3]},
                s0c = {sv0[4], sv0[5]}, s0d = {sv0[6], sv0[7]};
    const f16x2 s1a = {sv1[0], sv1[1]}, s1b = {sv1[2], sv1[3]},
                s1c = {sv1[4], sv1[5]}, s1d = {sv1[6], sv1[7]};

    f32x16 acc00 = {}, acc01 = {}, acc10 = {}, acc11 = {};

    const float* f0 = fb + ((size_t)lh << 15);       // lane-half's first row

#pragma unroll 4
    for (int kk = 0; kk < 32; ++kk) {
        // A-frags for both o-tiles (contiguous, conflict-free)
        f16x8 a0 = *(const f16x8*)&lwb[((0 * 32 + kk) * 64 + lane) * 8];
        f16x8 a1 = *(const f16x8*)&lwb[((1 * 32 + kk) * 64 + lane) * 8];

        int off = kk << 16;                          // (kk*2)<<15 floats
        float fv0 = f0[off + pc0];
        float fv1 = f0[off + pc1];

        f16 h0 = (f16)fv0, h1 = (f16)fv1;
        f16x2 f0v = {h0, h0}, f1v = {h1, h1};
        f16x2 p0a = f0v * s0a, p0b = f0v * s0b, p0c = f0v * s0c, p0d = f0v * s0d;
        f16x2 p1a = f1v * s1a, p1b = f1v * s1b, p1c = f1v * s1c, p1d = f1v * s1d;
        f16x8 bv0 = {p0a[0],p0a[1],p0b[0],p0b[1],p0c[0],p0c[1],p0d[0],p0d[1]};
        f16x8 bv1 = {p1a[0],p1a[1],p1b[0],p1b[1],p1c[0],p1c[1],p1d[0],p1d[1]};

        acc00 = __builtin_amdgcn_mfma_f32_32x32x16_f16(a0, bv0, acc00, 0, 0, 0);
        acc01 = __builtin_amdgcn_mfma_f32_32x32x16_f16(a1, bv0, acc01, 0, 0, 0);
        acc10 = __builtin_amdgcn_mfma_f32_32x32x16_f16(a0, bv1, acc10, 0, 0, 0);
        acc11 = __builtin_amdgcn_mfma_f32_32x32x16_f16(a1, bv1, acc11, 0, 0, 0);
    }

    // ---- correction: acc += (-G)[grp] . s   (A k-slots 8..15 zeroed) ----
    {
        const f16x8 z = {};
        f16x8 g00 = *(const f16x8*)&G[(size_t)grp0 * 512 + (0 * 32 + l31) * 8];
        f16x8 g01 = *(const f16x8*)&G[(size_t)grp0 * 512 + (1 * 32 + l31) * 8];
        f16x8 g10 = *(const f16x8*)&G[(size_t)grp1 * 512 + (0 * 32 + l31) * 8];
        f16x8 g11 = *(const f16x8*)&G[(size_t)grp1 * 512 + (1 * 32 + l31) * 8];
        if (lh) { g00 = z; g01 = z; g10 = z; g11 = z; }
        acc00 = __builtin_amdgcn_mfma_f32_32x32x16_f16(g00, sv0, acc00, 0, 0, 0);
        acc01 = __builtin_amdgcn_mfma_f32_32x32x16_f16(g01, sv0, acc01, 0, 0, 0);
        acc10 = __builtin_amdgcn_mfma_f32_32x32x16_f16(g10, sv1, acc10, 0, 0, 0);
        acc11 = __builtin_amdgcn_mfma_f32_32x32x16_f16(g11, sv1, acc11, 0, 0, 0);
    }

    // ---------------- epilogue: BN + ReLU + coalesced store ------------------
    // C layout: col = lane&31, row = (r&3) + 8*(r>>2) + 4*lh
#pragma unroll
    for (int q = 0; q < 2; ++q) {
        int pcol = (q == 0) ? pc0 : pc1;
#pragma unroll
        for (int ot = 0; ot < 2; ++ot) {
            const f32x16& a = (q == 0) ? (ot == 0 ? acc00 : acc01)
                                       : (ot == 0 ? acc10 : acc11);
#pragma unroll
            for (int r = 0; r < 16; ++r) {
                int o = ot * 32 + (r & 3) + ((r >> 2) << 3) + (lh << 2);
                float v = a[r];
                v = v * (bn_g[o] * BNSCL) + bn_b[o];
                v = fmaxf(v, 0.f);
                out[((size_t)(b * 64 + o) << 15) + pcol] = v;
            }
        }
    }
}

// ---------------------------------------------------------------------------
extern "C" void kernel_launch(void* const* d_in, const int* in_sizes, int n_in,
                              void* d_out, int out_size, void* d_ws, size_t ws_size,
                              hipStream_t stream)
{
    const float* features = (const float*)d_in[0];
    const float* xyz      = (const float*)d_in[1];
    const float* w1  = (const float*)d_in[2];
    const float* g1  = (const float*)d_in[3];
    const float* be1 = (const float*)d_in[4];
    const float* w2  = (const float*)d_in[5];
    const float* g2  = (const float*)d_in[6];
    const float* be2 = (const float*)d_in[7];
    const float* w3  = (const float*)d_in[8];
    const float* g3  = (const float*)d_in[9];
    const float* be3 = (const float*)d_in[10];
    const float* w4  = (const float*)d_in[11];
    const float* b4  = (const float*)d_in[12];
    const float* wb  = (const float*)d_in[13];
    const float* bn_g = (const float*)d_in[14];
    const float* bn_b = (const float*)d_in[15];

    char* ws = (char*)d_ws;
    f16* scores = (f16*)ws;                          // 4 MB
    f16* G      = (f16*)(ws + (4u  << 20));          // 8 MB
    f16* wpf    = (f16*)(ws + (12u << 20));          // 128 KB
    f16* wdb    = (f16*)(ws + (12u << 20) + (256u << 10)); // 64 KB

    k_scores<<<512, 256, 0, stream>>>(xyz, w1, g1, be1, w2, g2, be2,
                                      w3, g3, be3, w4, b4, wb, wpf, wdb, scores);
    k_gprep<<<256, 256, 0, stream>>>(features, wdb, G);
    k_main<<<512, 512, 0, stream>>>(features, scores, wpf, G, bn_g, bn_b,
                                    (float*)d_out);
}